// Round 1
// baseline (246.903 us; speedup 1.0000x reference)
//
#include <hip/hip_runtime.h>

// XConv: N=32 P=1024 K=16 DIMS=3 C_IN=64 C_MID=64 C_OUT=128 DM=2; NP=32768
// fp32 throughout. ws usage: 32768*256 floats (33.5 MB): holds X2^T, overwritten in-place by tmp.

#define ELU(x) ((x) > 0.0f ? (x) : (__expf(x) - 1.0f))

__device__ __forceinline__ void lds_fence() {
    asm volatile("s_waitcnt lgkmcnt(0)" ::: "memory");
}

// ---------------- Kernel 1: X-transform (pl -> Xc -> dep1 -> dep2 -> X2^T) ----------------
// LDS float offsets
#define A_WCT   0        // wconv^T: (d*16+k)*256 + o            (12288)
#define A_BCONV 12288    // 256
#define A_WD1   12544    // wdep1: i*324 + j*20 + k              (5184)
#define A_WD2   17728    // wdep2 same                           (5184)
#define A_BD1   22912    // i*16+j                               (256)
#define A_BD2   23168    // 256
#define A_WAVE  23424    // + wave*704: pl[64] (k*4+d) | X0T @+64 (i*20+k) | Y @+384 (j*20+i)
#define A_WAVE_SZ 704
#define A_TOTAL (23424 + 16*704)   // 34688 floats = 138752 B

__global__ __launch_bounds__(1024) void k_xform(
    const float* __restrict__ rep, const float* __restrict__ pts,
    const float* __restrict__ wconv, const float* __restrict__ bconv,
    const float* __restrict__ wdep1, const float* __restrict__ bdep1,
    const float* __restrict__ wdep2, const float* __restrict__ bdep2,
    float* __restrict__ x2t)
{
    extern __shared__ __align__(16) float sm[];
    const int tid = threadIdx.x;

    for (int e = tid; e < 12288; e += 1024) {
        int o = e / 48, r = e % 48;          // r = d*16+k
        sm[A_WCT + r*256 + o] = wconv[e];
    }
    for (int e = tid; e < 4096; e += 1024) {
        int i = e >> 8, j = (e >> 4) & 15, k = e & 15;
        sm[A_WD1 + i*324 + j*20 + k] = wdep1[e];
        sm[A_WD2 + i*324 + j*20 + k] = wdep2[e];
    }
    if (tid < 256) {
        sm[A_BCONV + tid] = bconv[tid];
        sm[A_BD1 + tid]   = bdep1[tid];
        sm[A_BD2 + tid]   = bdep2[tid];
    }
    __syncthreads();

    const int wave = tid >> 6, lane = tid & 63;
    const int wb = A_WAVE + wave * A_WAVE_SZ;
    const int iL = lane & 15, jq = lane >> 4;

    for (int it = 0; it < 8; ++it) {
        const int pt = blockIdx.x * 128 + it * 16 + wave;
        if (lane < 48) {
            const int k = lane / 3, d = lane - 3 * k;
            sm[wb + k*4 + d] = pts[pt*48 + lane] - rep[pt*3 + d];
        }
        lds_fence();
        // Xc[o] = elu(sum_{k,d} pl[k][d]*wconv[o][d][k] + bconv[o]); lane owns o=4L..4L+3
        float a0, a1, a2, a3;
        {
            const float4 b = *(const float4*)&sm[A_BCONV + 4*lane];
            a0 = b.x; a1 = b.y; a2 = b.z; a3 = b.w;
        }
        #pragma unroll
        for (int k = 0; k < 16; ++k) {
            const float4 p  = *(const float4*)&sm[wb + k*4];
            const float4 w0 = *(const float4*)&sm[A_WCT + (k     )*256 + 4*lane]; // d=0
            const float4 wA = *(const float4*)&sm[A_WCT + (16 + k)*256 + 4*lane]; // d=1
            const float4 wB = *(const float4*)&sm[A_WCT + (32 + k)*256 + 4*lane]; // d=2
            a0 += p.x*w0.x + p.y*wA.x + p.z*wB.x;
            a1 += p.x*w0.y + p.y*wA.y + p.z*wB.y;
            a2 += p.x*w0.z + p.y*wA.z + p.z*wB.z;
            a3 += p.x*w0.w + p.y*wA.w + p.z*wB.w;
        }
        a0 = ELU(a0); a1 = ELU(a1); a2 = ELU(a2); a3 = ELU(a3);
        {
            // o = 4L+t -> X0[k'][i], k'=o>>4=L>>2, i=(o&15)=4*(L&3)+t ; store X0T[i][k']
            const int kp = lane >> 2, ib = (lane & 3) * 4;
            sm[wb + 64 + (ib+0)*20 + kp] = a0;
            sm[wb + 64 + (ib+1)*20 + kp] = a1;
            sm[wb + 64 + (ib+2)*20 + kp] = a2;
            sm[wb + 64 + (ib+3)*20 + kp] = a3;
        }
        lds_fence();
        // X1[i][j] = elu(sum_k X0[k][i]*wdep1[i][j][k] + bdep1[i][j]); store Y[j][i]=X1[i][j]
        {
            float xr[16];
            #pragma unroll
            for (int kb = 0; kb < 4; ++kb) {
                const float4 v = *(const float4*)&sm[wb + 64 + iL*20 + 4*kb];
                xr[4*kb+0]=v.x; xr[4*kb+1]=v.y; xr[4*kb+2]=v.z; xr[4*kb+3]=v.w;
            }
            #pragma unroll
            for (int jj = 0; jj < 4; ++jj) {
                const int j = jq*4 + jj;
                float acc = sm[A_BD1 + iL*16 + j];
                #pragma unroll
                for (int kb = 0; kb < 4; ++kb) {
                    const float4 w = *(const float4*)&sm[A_WD1 + iL*324 + j*20 + 4*kb];
                    acc += xr[4*kb]*w.x + xr[4*kb+1]*w.y + xr[4*kb+2]*w.z + xr[4*kb+3]*w.w;
                }
                sm[wb + 384 + j*20 + iL] = ELU(acc);
            }
        }
        lds_fence();
        // X2[i][j] = sum_k X1[k][i]*wdep2[i][j][k] + bdep2[i][j] (no elu); write x2t[pt][j][i]
        {
            float yr[16];
            #pragma unroll
            for (int kb = 0; kb < 4; ++kb) {
                const float4 v = *(const float4*)&sm[wb + 384 + iL*20 + 4*kb];
                yr[4*kb+0]=v.x; yr[4*kb+1]=v.y; yr[4*kb+2]=v.z; yr[4*kb+3]=v.w;
            }
            #pragma unroll
            for (int jj = 0; jj < 4; ++jj) {
                const int j = jq*4 + jj;
                float acc = sm[A_BD2 + iL*16 + j];
                #pragma unroll
                for (int kb = 0; kb < 4; ++kb) {
                    const float4 w = *(const float4*)&sm[A_WD2 + iL*324 + j*20 + 4*kb];
                    acc += yr[4*kb]*w.x + yr[4*kb+1]*w.y + yr[4*kb+2]*w.z + yr[4*kb+3]*w.w;
                }
                x2t[pt*256 + j*16 + iL] = acc;
            }
        }
        lds_fence();
    }
}

// ---------------- Kernel 2: features (h1 -> h2 -> cat -> fts_X -> tmp) ----------------
#define B_W1   0      // d*64+c (192)
#define B_B1   192    // 64
#define B_W2   256    // j*64+c (4096)
#define B_B2   4352   // 64
#define B_WDW  4416   // m*2048 + k*128 + c (4096)
#define B_BDW  8512   // c*2+m (256)
#define B_WAVE 8768   // + wave*3712: pl[64] | h1T @+64 (c*20+k, 1280) | cat @+1344 (k*128+c, 2048) | X2T @+3392 (j*20+k, 320)
#define B_WAVE_SZ 3712
#define B_TOTAL (8768 + 8*3712)  // 38464 floats = 153856 B

__global__ __launch_bounds__(512) void k_feat(
    const float* __restrict__ rep, const float* __restrict__ pts, const float* __restrict__ fts,
    const float* __restrict__ w1, const float* __restrict__ b1,
    const float* __restrict__ w2, const float* __restrict__ b2,
    const float* __restrict__ wdw, const float* __restrict__ bdw,
    float* __restrict__ xbuf /* read X2T, overwrite with tmp */)
{
    extern __shared__ __align__(16) float sm[];
    const int tid = threadIdx.x;
    for (int e = tid; e < 192; e += 512) sm[B_W1 + e] = w1[e];
    if (tid < 64) { sm[B_B1 + tid] = b1[tid]; sm[B_B2 + tid] = b2[tid]; }
    for (int e = tid; e < 4096; e += 512) sm[B_W2 + e] = w2[e];
    for (int e = tid; e < 4096; e += 512) {
        const int c = e >> 5, m = (e >> 4) & 1, k = e & 15;
        sm[B_WDW + m*2048 + k*128 + c] = wdw[e];
    }
    if (tid < 256) sm[B_BDW + tid] = bdw[tid];
    __syncthreads();

    const int wave = tid >> 6, lane = tid & 63;
    const int wb = B_WAVE + wave * B_WAVE_SZ;
    const int kq = lane >> 4, cq = lane & 15;

    for (int it = 0; it < 16; ++it) {
        const int pt = blockIdx.x * 128 + it * 8 + wave;
        // ---- phase 0: issue global loads, write pl
        float4 fr[4];
        #pragma unroll
        for (int ii = 0; ii < 4; ++ii)
            fr[ii] = *(const float4*)&fts[pt*1024 + (ii*64 + lane)*4];
        const float4 x2v = *(const float4*)&xbuf[pt*256 + 4*lane];
        if (lane < 48) {
            const int k = lane / 3, d = lane - 3 * k;
            sm[wb + k*4 + d] = pts[pt*48 + lane] - rep[pt*3 + d];
        }
        lds_fence();
        // ---- phase 1: h1 (lane = column c), write h1T[c][k]; stage X2T + fts->cat
        {
            const float w1x = sm[B_W1 + lane], w1y = sm[B_W1 + 64 + lane], w1z = sm[B_W1 + 128 + lane];
            const float b1v = sm[B_B1 + lane];
            float h1r[16];
            #pragma unroll
            for (int k = 0; k < 16; ++k) {
                const float4 p = *(const float4*)&sm[wb + k*4];
                h1r[k] = ELU(b1v + p.x*w1x + p.y*w1y + p.z*w1z);
            }
            #pragma unroll
            for (int kb = 0; kb < 4; ++kb) {
                const float4 v = make_float4(h1r[4*kb], h1r[4*kb+1], h1r[4*kb+2], h1r[4*kb+3]);
                *(float4*)&sm[wb + 64 + lane*20 + 4*kb] = v;
            }
        }
        {   // X2T: xbuf[pt][j][k] -> lds [j][k] (stride 20)
            const int j = lane >> 2, k0 = (lane & 3) * 4;
            *(float4*)&sm[wb + 3392 + j*20 + k0] = x2v;
        }
        #pragma unroll
        for (int ii = 0; ii < 4; ++ii) {   // fts -> cat[k][64+c]
            const int idx4 = ii*64 + lane;
            const int k = idx4 >> 4, c4 = (idx4 & 15) * 4;
            *(float4*)&sm[wb + 1344 + k*128 + 64 + c4] = fr[ii];
        }
        lds_fence();
        // ---- phase 2: h2[k][c] = elu(sum_j h1[k][j]*w2[j][c] + b2[c]); 4x4 tile per lane
        {
            float acc[4][4];
            {
                const float4 b2v = *(const float4*)&sm[B_B2 + 4*cq];
                #pragma unroll
                for (int ki = 0; ki < 4; ++ki) {
                    acc[ki][0] = b2v.x; acc[ki][1] = b2v.y; acc[ki][2] = b2v.z; acc[ki][3] = b2v.w;
                }
            }
            #pragma unroll 4
            for (int j = 0; j < 64; ++j) {
                const float4 a = *(const float4*)&sm[wb + 64 + j*20 + 4*kq];   // h1[4kq..][j]
                const float4 w = *(const float4*)&sm[B_W2 + j*64 + 4*cq];      // w2[j][4cq..]
                acc[0][0] += a.x*w.x; acc[0][1] += a.x*w.y; acc[0][2] += a.x*w.z; acc[0][3] += a.x*w.w;
                acc[1][0] += a.y*w.x; acc[1][1] += a.y*w.y; acc[1][2] += a.y*w.z; acc[1][3] += a.y*w.w;
                acc[2][0] += a.z*w.x; acc[2][1] += a.z*w.y; acc[2][2] += a.z*w.z; acc[2][3] += a.z*w.w;
                acc[3][0] += a.w*w.x; acc[3][1] += a.w*w.y; acc[3][2] += a.w*w.z; acc[3][3] += a.w*w.w;
            }
            #pragma unroll
            for (int ki = 0; ki < 4; ++ki) {
                const float4 v = make_float4(ELU(acc[ki][0]), ELU(acc[ki][1]), ELU(acc[ki][2]), ELU(acc[ki][3]));
                *(float4*)&sm[wb + 1344 + (4*kq + ki)*128 + 4*cq] = v;
            }
        }
        lds_fence();
        // ---- phase 3: fts_X[k][c] = sum_j X2[k][j]*cat[j][c]; lane owns c0=2L, c1=2L+1
        float fx0[16], fx1[16];
        #pragma unroll
        for (int k = 0; k < 16; ++k) { fx0[k] = 0.f; fx1[k] = 0.f; }
        #pragma unroll 2
        for (int j = 0; j < 16; ++j) {
            float xr[16];
            #pragma unroll
            for (int kb = 0; kb < 4; ++kb) {
                const float4 v = *(const float4*)&sm[wb + 3392 + j*20 + 4*kb]; // broadcast
                xr[4*kb+0]=v.x; xr[4*kb+1]=v.y; xr[4*kb+2]=v.z; xr[4*kb+3]=v.w;
            }
            const float2 cv = *(const float2*)&sm[wb + 1344 + j*128 + 2*lane];
            #pragma unroll
            for (int k = 0; k < 16; ++k) { fx0[k] += xr[k]*cv.x; fx1[k] += xr[k]*cv.y; }
        }
        // ---- phase 4: tmp[c][m] = sum_k fts_X[k][c]*wdw[c][m][k] + bdw[c][m]
        {
            float t00 = 0.f, t01 = 0.f, t10 = 0.f, t11 = 0.f;
            #pragma unroll
            for (int k = 0; k < 16; ++k) {
                const float2 wm0 = *(const float2*)&sm[B_WDW +        k*128 + 2*lane]; // m=0: (c0,c1)
                const float2 wm1 = *(const float2*)&sm[B_WDW + 2048 + k*128 + 2*lane]; // m=1
                t00 += fx0[k]*wm0.x; t10 += fx1[k]*wm0.y;
                t01 += fx0[k]*wm1.x; t11 += fx1[k]*wm1.y;
            }
            const float4 bv = *(const float4*)&sm[B_BDW + 4*lane];
            const float4 r = make_float4(t00 + bv.x, t01 + bv.y, t10 + bv.z, t11 + bv.w);
            *(float4*)&xbuf[pt*256 + 4*lane] = r;   // overwrite X2T slot (already consumed)
        }
        lds_fence();
    }
}

// ---------------- Kernel 3: out = elu(tmp(NP,256) @ wpw^T(256,128) + bpw) ----------------
__global__ __launch_bounds__(256) void k_out(
    const float* __restrict__ tmp, const float* __restrict__ wpw,
    const float* __restrict__ bpw, float* __restrict__ out)
{
    __shared__ __align__(16) float At[64*72];   // [k][row], padded stride 72
    __shared__ __align__(16) float Bs[64*128];  // [k][o]
    const int tid = threadIdx.x;
    const int row0 = blockIdx.x * 64;
    const int tr = tid >> 5, tc = tid & 31;     // rows 8tr..+7, cols 4tc..+3
    float acc[8][4];
    #pragma unroll
    for (int i = 0; i < 8; ++i)
        #pragma unroll
        for (int j = 0; j < 4; ++j) acc[i][j] = 0.f;

    for (int kb = 0; kb < 4; ++kb) {
        #pragma unroll
        for (int i = 0; i < 16; ++i) {
            const int e = tid + i*256;            // 0..4095
            const int r = e >> 6, k = e & 63;
            At[k*72 + r] = tmp[(row0 + r)*256 + kb*64 + k];
        }
        #pragma unroll
        for (int i = 0; i < 32; ++i) {
            const int e = tid + i*256;            // 0..8191
            const int o = e >> 6, k = e & 63;
            Bs[k*128 + o] = wpw[o*256 + kb*64 + k];
        }
        __syncthreads();
        #pragma unroll 4
        for (int k = 0; k < 64; ++k) {
            const float4 aa = *(const float4*)&At[k*72 + 8*tr];
            const float4 ab = *(const float4*)&At[k*72 + 8*tr + 4];
            const float4 bv = *(const float4*)&Bs[k*128 + 4*tc];
            const float av[8] = {aa.x, aa.y, aa.z, aa.w, ab.x, ab.y, ab.z, ab.w};
            #pragma unroll
            for (int ri = 0; ri < 8; ++ri) {
                acc[ri][0] += av[ri]*bv.x; acc[ri][1] += av[ri]*bv.y;
                acc[ri][2] += av[ri]*bv.z; acc[ri][3] += av[ri]*bv.w;
            }
        }
        __syncthreads();
    }
    const float4 bb = *(const float4*)&bpw[4*tc];
    #pragma unroll
    for (int ri = 0; ri < 8; ++ri) {
        float4 r;
        r.x = ELU(acc[ri][0] + bb.x);
        r.y = ELU(acc[ri][1] + bb.y);
        r.z = ELU(acc[ri][2] + bb.z);
        r.w = ELU(acc[ri][3] + bb.w);
        *(float4*)&out[(row0 + 8*tr + ri)*128 + 4*tc] = r;
    }
}

extern "C" void kernel_launch(void* const* d_in, const int* in_sizes, int n_in,
                              void* d_out, int out_size, void* d_ws, size_t ws_size,
                              hipStream_t stream)
{
    (void)in_sizes; (void)n_in; (void)out_size; (void)ws_size;
    const float* rep   = (const float*)d_in[0];
    const float* pts   = (const float*)d_in[1];
    const float* fts   = (const float*)d_in[2];
    const float* w1    = (const float*)d_in[3];
    const float* b1    = (const float*)d_in[4];
    const float* w2    = (const float*)d_in[5];
    const float* b2    = (const float*)d_in[6];
    const float* wconv = (const float*)d_in[7];
    const float* bconv = (const float*)d_in[8];
    const float* wdep1 = (const float*)d_in[9];
    const float* bdep1 = (const float*)d_in[10];
    const float* wdep2 = (const float*)d_in[11];
    const float* bdep2 = (const float*)d_in[12];
    const float* wdw   = (const float*)d_in[13];
    const float* bdw   = (const float*)d_in[14];
    const float* wpw   = (const float*)d_in[15];
    const float* bpw   = (const float*)d_in[16];
    float* out  = (float*)d_out;
    float* xbuf = (float*)d_ws;   // 32768*256 floats = 33.5 MB

    hipFuncSetAttribute((const void*)k_xform, hipFuncAttributeMaxDynamicSharedMemorySize, A_TOTAL*4);
    hipFuncSetAttribute((const void*)k_feat,  hipFuncAttributeMaxDynamicSharedMemorySize, B_TOTAL*4);

    k_xform<<<dim3(256), dim3(1024), A_TOTAL*4, stream>>>(rep, pts, wconv, bconv, wdep1, bdep1, wdep2, bdep2, xbuf);
    k_feat <<<dim3(256), dim3(512),  B_TOTAL*4, stream>>>(rep, pts, fts, w1, b1, w2, b2, wdw, bdw, xbuf);
    k_out  <<<dim3(512), dim3(256),  0, stream>>>(xbuf, wpw, bpw, out);
}

// Round 2
// 201.444 us; speedup vs baseline: 1.2257x; 1.2257x over previous
//
#include <hip/hip_runtime.h>
#include <hip/hip_bf16.h>

// XConv: N=32 P=1024 K=16 DIMS=3 C_IN=64 C_MID=64 C_OUT=128 DM=2; NP=32768
// ws: 32768*256 floats (33.5 MB): holds X2 (untransposed), overwritten in-place by tmp.

#define ELU(x) ((x) > 0.0f ? (x) : (__expf(x) - 1.0f))

__device__ __forceinline__ void lds_fence() {
    asm volatile("s_waitcnt lgkmcnt(0)" ::: "memory");
}

typedef __attribute__((ext_vector_type(8))) short short8v;
typedef __attribute__((ext_vector_type(4))) float f32x4;
#define MFMA32(a, b, c) __builtin_amdgcn_mfma_f32_16x16x32_bf16(a, b, c, 0, 0, 0)

__device__ __forceinline__ short f2bf(float x) {
    __hip_bfloat16 h = __float2bfloat16(x);
    return *reinterpret_cast<short*>(&h);
}

// ---------------- Kernel 1: X-transform (pl -> Xc -> dep1 -> dep2 -> X2) ----------------
#define A_WCT   0        // wconv^T: (d*16+k)*256 + o            (12288)
#define A_BCONV 12288    // 256
#define A_WD1   12544    // wdep1: i*324 + j*20 + k              (5184)
#define A_WD2   17728    // wdep2 same                           (5184)
#define A_BD1   22912    // i*16+j                               (256)
#define A_BD2   23168    // 256
#define A_WAVE  23424    // + wave*704: pl[64] (k*4+d) | X0T @+64 (i*20+k) | Y @+384 (j*20+i)
#define A_WAVE_SZ 704
#define A_TOTAL (23424 + 16*704)   // 34688 floats = 138752 B

__global__ __launch_bounds__(1024) void k_xform(
    const float* __restrict__ rep, const float* __restrict__ pts,
    const float* __restrict__ wconv, const float* __restrict__ bconv,
    const float* __restrict__ wdep1, const float* __restrict__ bdep1,
    const float* __restrict__ wdep2, const float* __restrict__ bdep2,
    float* __restrict__ x2)
{
    extern __shared__ __align__(16) float sm[];
    const int tid = threadIdx.x;

    for (int e = tid; e < 12288; e += 1024) {
        int o = e / 48, r = e % 48;          // r = d*16+k
        sm[A_WCT + r*256 + o] = wconv[e];
    }
    for (int e = tid; e < 4096; e += 1024) {
        int i = e >> 8, j = (e >> 4) & 15, k = e & 15;
        sm[A_WD1 + i*324 + j*20 + k] = wdep1[e];
        sm[A_WD2 + i*324 + j*20 + k] = wdep2[e];
    }
    if (tid < 256) {
        sm[A_BCONV + tid] = bconv[tid];
        sm[A_BD1 + tid]   = bdep1[tid];
        sm[A_BD2 + tid]   = bdep2[tid];
    }
    __syncthreads();

    const int wave = tid >> 6, lane = tid & 63;
    const int wb = A_WAVE + wave * A_WAVE_SZ;
    const int iL = lane & 15, jq = lane >> 4;

    for (int it = 0; it < 8; ++it) {
        const int pt = blockIdx.x * 128 + it * 16 + wave;
        if (lane < 48) {
            const int k = lane / 3, d = lane - 3 * k;
            sm[wb + k*4 + d] = pts[pt*48 + lane] - rep[pt*3 + d];
        }
        lds_fence();
        // Xc[o] = elu(sum_{k,d} pl[k][d]*wconv[o][d][k] + bconv[o]); lane owns o=4L..4L+3
        float a0, a1, a2, a3;
        {
            const float4 b = *(const float4*)&sm[A_BCONV + 4*lane];
            a0 = b.x; a1 = b.y; a2 = b.z; a3 = b.w;
        }
        #pragma unroll
        for (int k = 0; k < 16; ++k) {
            const float4 p  = *(const float4*)&sm[wb + k*4];
            const float4 w0 = *(const float4*)&sm[A_WCT + (k     )*256 + 4*lane];
            const float4 wA = *(const float4*)&sm[A_WCT + (16 + k)*256 + 4*lane];
            const float4 wB = *(const float4*)&sm[A_WCT + (32 + k)*256 + 4*lane];
            a0 += p.x*w0.x + p.y*wA.x + p.z*wB.x;
            a1 += p.x*w0.y + p.y*wA.y + p.z*wB.y;
            a2 += p.x*w0.z + p.y*wA.z + p.z*wB.z;
            a3 += p.x*w0.w + p.y*wA.w + p.z*wB.w;
        }
        a0 = ELU(a0); a1 = ELU(a1); a2 = ELU(a2); a3 = ELU(a3);
        {
            const int kp = lane >> 2, ib = (lane & 3) * 4;
            sm[wb + 64 + (ib+0)*20 + kp] = a0;
            sm[wb + 64 + (ib+1)*20 + kp] = a1;
            sm[wb + 64 + (ib+2)*20 + kp] = a2;
            sm[wb + 64 + (ib+3)*20 + kp] = a3;
        }
        lds_fence();
        // X1[i][j] = elu(sum_k X0[k][i]*wdep1[i][j][k] + bdep1[i][j]); store Y[j][i]
        {
            float xr[16];
            #pragma unroll
            for (int kb = 0; kb < 4; ++kb) {
                const float4 v = *(const float4*)&sm[wb + 64 + iL*20 + 4*kb];
                xr[4*kb+0]=v.x; xr[4*kb+1]=v.y; xr[4*kb+2]=v.z; xr[4*kb+3]=v.w;
            }
            #pragma unroll
            for (int jj = 0; jj < 4; ++jj) {
                const int j = jq*4 + jj;
                float acc = sm[A_BD1 + iL*16 + j];
                #pragma unroll
                for (int kb = 0; kb < 4; ++kb) {
                    const float4 w = *(const float4*)&sm[A_WD1 + iL*324 + j*20 + 4*kb];
                    acc += xr[4*kb]*w.x + xr[4*kb+1]*w.y + xr[4*kb+2]*w.z + xr[4*kb+3]*w.w;
                }
                sm[wb + 384 + j*20 + iL] = ELU(acc);
            }
        }
        lds_fence();
        // X2[i][j] = sum_k X1[k][i]*wdep2[i][j][k] + bdep2[i][j]; store UNTRANSPOSED x2[pt][i][j]
        {
            float yr[16];
            #pragma unroll
            for (int kb = 0; kb < 4; ++kb) {
                const float4 v = *(const float4*)&sm[wb + 384 + iL*20 + 4*kb];
                yr[4*kb+0]=v.x; yr[4*kb+1]=v.y; yr[4*kb+2]=v.z; yr[4*kb+3]=v.w;
            }
            float rr[4];
            #pragma unroll
            for (int jj = 0; jj < 4; ++jj) {
                const int j = jq*4 + jj;
                float acc = sm[A_BD2 + iL*16 + j];
                #pragma unroll
                for (int kb = 0; kb < 4; ++kb) {
                    const float4 w = *(const float4*)&sm[A_WD2 + iL*324 + j*20 + 4*kb];
                    acc += yr[4*kb]*w.x + yr[4*kb+1]*w.y + yr[4*kb+2]*w.z + yr[4*kb+3]*w.w;
                }
                rr[jj] = acc;
            }
            *(float4*)&x2[pt*256 + iL*16 + jq*4] = make_float4(rr[0], rr[1], rr[2], rr[3]);
        }
        lds_fence();
    }
}

// ---------------- Kernel 2: MFMA features (h1 -> h2 -> cat -> fts_X -> tmp) ----------------
// Per wave: 16 points, fully in-register via MFMA fragments. LDS holds only wdw (swizzled) + bdw.
// Layouts (verified m89): A[m][k]: m=l&15, k=(l>>4)*8+e ; B[k][n]: n=l&15, k=(l>>4)*8+e ;
// C[m][n]: n=l&15, m=(l>>4)*4+q.
// K=16 contractions embedded in K=32 via sigma(j)=8*(j>>2)+(j&3): e-slots 0-3 real, 4-7 zero.
__global__ __launch_bounds__(256, 2) void k_feat(
    const float* __restrict__ rep, const float* __restrict__ pts, const float* __restrict__ fts,
    const float* __restrict__ w1, const float* __restrict__ b1,
    const float* __restrict__ w2, const float* __restrict__ b2,
    const float* __restrict__ wdw, const float* __restrict__ bdw,
    float* __restrict__ xbuf)
{
    __shared__ __align__(16) float swdw[4096];   // [m][c][k^((c&3)<<2)] -> conflict-free b128
    __shared__ float sbdw[256];
    const int tid = threadIdx.x;
    for (int e = tid; e < 4096; e += 256) {
        const int c = e >> 5, m = (e >> 4) & 1, k = e & 15;
        swdw[m*2048 + c*16 + (k ^ ((c & 3) << 2))] = wdw[e];
    }
    sbdw[tid] = bdw[tid & 255];
    __syncthreads();

    const int lane = tid & 63, wave = tid >> 6;
    const int g = lane >> 4, s = lane & 15;

    // ---- one-time per-lane constants ----
    short8v w2f[4][2];
    #pragma unroll
    for (int nt = 0; nt < 4; ++nt)
        #pragma unroll
        for (int h = 0; h < 2; ++h) {
            short8v f;
            #pragma unroll
            for (int e = 0; e < 8; ++e)
                f[e] = f2bf(w2[(h*32 + g*8 + e)*64 + nt*16 + s]);
            w2f[nt][h] = f;
        }
    float w1v[16][3], b1v[16];
    #pragma unroll
    for (int t = 0; t < 2; ++t)
        #pragma unroll
        for (int e = 0; e < 8; ++e) {
            const int j = t*32 + g*8 + e;
            w1v[t*8+e][0] = w1[j]; w1v[t*8+e][1] = w1[64 + j]; w1v[t*8+e][2] = w1[128 + j];
            b1v[t*8+e] = b1[j];
        }
    float b2c[4];
    #pragma unroll
    for (int nt = 0; nt < 4; ++nt) b2c[nt] = b2[nt*16 + s];

    const int gw = blockIdx.x * 4 + wave;   // 0..2047
    const int pt0 = gw * 16;

    // ---- prefetch point pt0 ----
    float pf_f[16]; float4 pf_x; float pf_p0, pf_p1, pf_p2;
    {
        const int pt = pt0;
        #pragma unroll
        for (int ct = 0; ct < 4; ++ct)
            #pragma unroll
            for (int e = 0; e < 4; ++e)
                pf_f[ct*4+e] = fts[pt*1024 + (g*4 + e)*64 + ct*16 + s];
        pf_x = *(const float4*)&xbuf[pt*256 + s*16 + g*4];
        pf_p0 = pts[pt*48 + s*3 + 0] - rep[pt*3 + 0];
        pf_p1 = pts[pt*48 + s*3 + 1] - rep[pt*3 + 1];
        pf_p2 = pts[pt*48 + s*3 + 2] - rep[pt*3 + 2];
    }

    for (int it = 0; it < 16; ++it) {
        const int pt = pt0 + it;
        // consume prefetch
        float cur_f[16];
        #pragma unroll
        for (int i = 0; i < 16; ++i) cur_f[i] = pf_f[i];
        const float4 cur_x = pf_x;
        const float p0 = pf_p0, p1 = pf_p1, p2 = pf_p2;
        // issue next point's loads
        if (it < 15) {
            const int np = pt + 1;
            #pragma unroll
            for (int ct = 0; ct < 4; ++ct)
                #pragma unroll
                for (int e = 0; e < 4; ++e)
                    pf_f[ct*4+e] = fts[np*1024 + (g*4 + e)*64 + ct*16 + s];
            pf_x = *(const float4*)&xbuf[np*256 + s*16 + g*4];
            pf_p0 = pts[np*48 + s*3 + 0] - rep[np*3 + 0];
            pf_p1 = pts[np*48 + s*3 + 1] - rep[np*3 + 1];
            pf_p2 = pts[np*48 + s*3 + 2] - rep[np*3 + 2];
        }

        // ---- phase A: h1 in A-frag layout; h2 via 8 MFMA ----
        short8v af0, af1;
        #pragma unroll
        for (int t = 0; t < 2; ++t) {
            short8v f;
            #pragma unroll
            for (int e = 0; e < 8; ++e) {
                float h = b1v[t*8+e] + p0*w1v[t*8+e][0] + p1*w1v[t*8+e][1] + p2*w1v[t*8+e][2];
                h = ELU(h);
                f[e] = f2bf(h);
            }
            if (t == 0) af0 = f; else af1 = f;
        }
        f32x4 hacc[4];
        #pragma unroll
        for (int nt = 0; nt < 4; ++nt) {
            f32x4 a; a[0] = b2c[nt]; a[1] = b2c[nt]; a[2] = b2c[nt]; a[3] = b2c[nt];
            a = MFMA32(af0, w2f[nt][0], a);
            a = MFMA32(af1, w2f[nt][1], a);
            hacc[nt] = a;
        }

        // ---- X2 A-frag (K=16 embedded: slots 0-3) ----
        short8v a2 = (short8v)0;
        a2[0] = f2bf(cur_x.x); a2[1] = f2bf(cur_x.y);
        a2[2] = f2bf(cur_x.z); a2[3] = f2bf(cur_x.w);

        // ---- phase B+C fused per 16-col tile u: catB -> fts_X -> depthwise + reduce ----
        #pragma unroll
        for (int u = 0; u < 8; ++u) {
            short8v bfrag = (short8v)0;
            if (u < 4) {
                #pragma unroll
                for (int q = 0; q < 4; ++q) bfrag[q] = f2bf(ELU(hacc[u][q]));
            } else {
                #pragma unroll
                for (int e = 0; e < 4; ++e) bfrag[e] = f2bf(cur_f[(u-4)*4 + e]);
            }
            f32x4 z; z[0] = 0.f; z[1] = 0.f; z[2] = 0.f; z[3] = 0.f;
            const f32x4 fx = MFMA32(a2, bfrag, z);   // fts_X[4g+q][u*16+s]

            const int c = u*16 + s;
            const int ka = c*16 + 4*(g ^ (s & 3));
            const float4 wm0 = *(const float4*)&swdw[ka];
            const float4 wm1 = *(const float4*)&swdw[2048 + ka];
            float q0 = fx[0]*wm0.x + fx[1]*wm0.y + fx[2]*wm0.z + fx[3]*wm0.w;
            float q1 = fx[0]*wm1.x + fx[1]*wm1.y + fx[2]*wm1.z + fx[3]*wm1.w;
            q0 += __shfl_xor(q0, 16); q0 += __shfl_xor(q0, 32);
            q1 += __shfl_xor(q1, 16); q1 += __shfl_xor(q1, 32);
            if (lane < 16) {
                float2 r; r.x = q0 + sbdw[2*c]; r.y = q1 + sbdw[2*c + 1];
                *(float2*)&xbuf[pt*256 + 2*c] = r;
            }
        }
    }
}

// ---------------- Kernel 3: out = elu(tmp(NP,256) @ wpw^T(256,128) + bpw) ----------------
__global__ __launch_bounds__(256) void k_out(
    const float* __restrict__ tmp, const float* __restrict__ wpw,
    const float* __restrict__ bpw, float* __restrict__ out)
{
    __shared__ __align__(16) float At[64*72];   // [k][row], padded stride 72
    __shared__ __align__(16) float Bs[64*128];  // [k][o]
    const int tid = threadIdx.x;
    const int row0 = blockIdx.x * 64;
    const int tr = tid >> 5, tc = tid & 31;     // rows 8tr..+7, cols 4tc..+3
    float acc[8][4];
    #pragma unroll
    for (int i = 0; i < 8; ++i)
        #pragma unroll
        for (int j = 0; j < 4; ++j) acc[i][j] = 0.f;

    for (int kb = 0; kb < 4; ++kb) {
        #pragma unroll
        for (int i = 0; i < 16; ++i) {
            const int e = tid + i*256;
            const int r = e >> 6, k = e & 63;
            At[k*72 + r] = tmp[(row0 + r)*256 + kb*64 + k];
        }
        #pragma unroll
        for (int i = 0; i < 32; ++i) {
            const int e = tid + i*256;
            const int o = e >> 6, k = e & 63;
            Bs[k*128 + o] = wpw[o*256 + kb*64 + k];
        }
        __syncthreads();
        #pragma unroll 4
        for (int k = 0; k < 64; ++k) {
            const float4 aa = *(const float4*)&At[k*72 + 8*tr];
            const float4 ab = *(const float4*)&At[k*72 + 8*tr + 4];
            const float4 bv = *(const float4*)&Bs[k*128 + 4*tc];
            const float av[8] = {aa.x, aa.y, aa.z, aa.w, ab.x, ab.y, ab.z, ab.w};
            #pragma unroll
            for (int ri = 0; ri < 8; ++ri) {
                acc[ri][0] += av[ri]*bv.x; acc[ri][1] += av[ri]*bv.y;
                acc[ri][2] += av[ri]*bv.z; acc[ri][3] += av[ri]*bv.w;
            }
        }
        __syncthreads();
    }
    const float4 bb = *(const float4*)&bpw[4*tc];
    #pragma unroll
    for (int ri = 0; ri < 8; ++ri) {
        float4 r;
        r.x = ELU(acc[ri][0] + bb.x);
        r.y = ELU(acc[ri][1] + bb.y);
        r.z = ELU(acc[ri][2] + bb.z);
        r.w = ELU(acc[ri][3] + bb.w);
        *(float4*)&out[(row0 + 8*tr + ri)*128 + 4*tc] = r;
    }
}

extern "C" void kernel_launch(void* const* d_in, const int* in_sizes, int n_in,
                              void* d_out, int out_size, void* d_ws, size_t ws_size,
                              hipStream_t stream)
{
    (void)in_sizes; (void)n_in; (void)out_size; (void)ws_size;
    const float* rep   = (const float*)d_in[0];
    const float* pts   = (const float*)d_in[1];
    const float* fts   = (const float*)d_in[2];
    const float* w1    = (const float*)d_in[3];
    const float* b1    = (const float*)d_in[4];
    const float* w2    = (const float*)d_in[5];
    const float* b2    = (const float*)d_in[6];
    const float* wconv = (const float*)d_in[7];
    const float* bconv = (const float*)d_in[8];
    const float* wdep1 = (const float*)d_in[9];
    const float* bdep1 = (const float*)d_in[10];
    const float* wdep2 = (const float*)d_in[11];
    const float* bdep2 = (const float*)d_in[12];
    const float* wdw   = (const float*)d_in[13];
    const float* bdw   = (const float*)d_in[14];
    const float* wpw   = (const float*)d_in[15];
    const float* bpw   = (const float*)d_in[16];
    float* out  = (float*)d_out;
    float* xbuf = (float*)d_ws;   // 32768*256 floats = 33.5 MB

    hipFuncSetAttribute((const void*)k_xform, hipFuncAttributeMaxDynamicSharedMemorySize, A_TOTAL*4);

    k_xform<<<dim3(256), dim3(1024), A_TOTAL*4, stream>>>(rep, pts, wconv, bconv, wdep1, bdep1, wdep2, bdep2, xbuf);
    k_feat <<<dim3(512), dim3(256), 0, stream>>>(rep, pts, fts, w1, b1, w2, b2, wdw, bdw, xbuf);
    k_out  <<<dim3(512), dim3(256), 0, stream>>>(xbuf, wpw, bpw, out);
}

// Round 3
// 188.100 us; speedup vs baseline: 1.3126x; 1.0709x over previous
//
#include <hip/hip_runtime.h>
#include <hip/hip_bf16.h>

// XConv: N=32 P=1024 K=16 DIMS=3 C_IN=64 C_MID=64 C_OUT=128 DM=2; NP=32768
// ws: 32768*256 floats (33.5 MB): holds X2 (untransposed), overwritten in-place by tmp.

#define ELU(x) ((x) > 0.0f ? (x) : (__expf(x) - 1.0f))

__device__ __forceinline__ void lds_fence() {
    asm volatile("s_waitcnt lgkmcnt(0)" ::: "memory");
}

typedef __attribute__((ext_vector_type(8))) short short8v;
typedef __attribute__((ext_vector_type(4))) float f32x4;
#define MFMA32(a, b, c) __builtin_amdgcn_mfma_f32_16x16x32_bf16(a, b, c, 0, 0, 0)

__device__ __forceinline__ short f2bf(float x) {
    __hip_bfloat16 h = __float2bfloat16(x);
    return *reinterpret_cast<short*>(&h);
}
__device__ __forceinline__ float bf2f(short x) {
    unsigned u = ((unsigned)(unsigned short)x) << 16;
    return __uint_as_float(u);
}

// ---------------- Kernel 1: X-transform via MFMA ----------------
// Per wave: 16 points. Xc = pl(16x48) @ wconvT(48x256) via MFMA (K=32 + K=16 embedded in
// slots e=0..3 of k_embed=g*8+e). A-side hi/lo bf16 split; B-side single bf16.
// C-layout: lane(g,s) holds Xc[point g*4+q][col u*16+s] -> i=s, k_tap=u: depthwise is lane-local
// over k, with an LDS transpose (stride-273 scratch) between dep1 and dep2.
#define XW_WC   0        // bf16 frag entries: idx=(part*16+u)*64+lane, 16B each (8192 words)
#define XW_WD1  8192     // wdep1: i*260 + j*16 + k  (4160 words)
#define XW_WD2  12352    // wdep2 same               (4160)
#define XW_BC   16512    // bconv 256
#define XW_BD1  16768    // 256
#define XW_BD2  17024    // 256
#define XW_SCR  17280    // + wave*4368 : per-point stride 273, scr[p*273 + j*17 + s]
#define XW_TOTAL (17280 + 4*4368)   // 34752 words = 139008 B

__global__ __launch_bounds__(256) void k_xform(
    const float* __restrict__ rep, const float* __restrict__ pts,
    const float* __restrict__ wconv, const float* __restrict__ bconv,
    const float* __restrict__ wdep1, const float* __restrict__ bdep1,
    const float* __restrict__ wdep2, const float* __restrict__ bdep2,
    float* __restrict__ x2)
{
    extern __shared__ __align__(16) float sm[];
    short* smh = (short*)sm;
    const int tid = threadIdx.x;

    // wconv -> bf16 B-frags
    for (int e = tid; e < 2048; e += 256) {
        const int part = e >> 10, u = (e >> 6) & 15, l = e & 63;
        const int g = l >> 4, s = l & 15;
        const int o = u * 16 + s;
        short8v v;
        if (part == 0) {
            #pragma unroll
            for (int t = 0; t < 8; ++t) v[t] = f2bf(wconv[o*48 + g*8 + t]);
        } else {
            #pragma unroll
            for (int t = 0; t < 4; ++t) v[t] = f2bf(wconv[o*48 + 32 + g*4 + t]);
            #pragma unroll
            for (int t = 4; t < 8; ++t) v[t] = 0;
        }
        *(short8v*)&smh[e * 8] = v;
    }
    for (int e = tid; e < 4096; e += 256) {
        const int i = e >> 8, j = (e >> 4) & 15, k = e & 15;
        sm[XW_WD1 + i*260 + j*16 + k] = wdep1[e];
        sm[XW_WD2 + i*260 + j*16 + k] = wdep2[e];
    }
    sm[XW_BC  + tid] = bconv[tid];
    sm[XW_BD1 + tid] = bdep1[tid];
    sm[XW_BD2 + tid] = bdep2[tid];
    __syncthreads();

    const int wave = tid >> 6, lane = tid & 63;
    const int g = lane >> 4, s = lane & 15;
    const int pt0 = (blockIdx.x * 4 + wave) * 16;

    // ---- A-frags: pl for point pt0+s, hi/lo split ----
    const int p = pt0 + s;
    const float r0 = rep[p*3], r1 = rep[p*3+1], r2 = rep[p*3+2];
    short8v ah0, al0, ah1, al1;
    #pragma unroll
    for (int e = 0; e < 8; ++e) {           // r = g*8+e : d = g>>1, k = r&15
        const int r = g*8 + e;
        const int d = g >> 1, k = r & 15;
        const float v = pts[p*48 + k*3 + d] - (d == 0 ? r0 : r1);
        const short h = f2bf(v);
        ah0[e] = h; al0[e] = f2bf(v - bf2f(h));
    }
    #pragma unroll
    for (int e = 0; e < 4; ++e) {           // r = 32+g*4+e : d=2, k=g*4+e
        const int k = g*4 + e;
        const float v = pts[p*48 + k*3 + 2] - r2;
        const short h = f2bf(v);
        ah1[e] = h; al1[e] = f2bf(v - bf2f(h));
    }
    #pragma unroll
    for (int e = 4; e < 8; ++e) { ah1[e] = 0; al1[e] = 0; }

    // ---- Xc via MFMA + ELU: ex[u][q] = X0[p=g*4+q][k_tap=u][i=s] ----
    f32x4 ex[16];
    #pragma unroll
    for (int u = 0; u < 16; ++u) {
        const float b = sm[XW_BC + u*16 + s];
        f32x4 acc; acc[0] = b; acc[1] = b; acc[2] = b; acc[3] = b;
        const short8v bh0 = *(const short8v*)&smh[(u*64 + lane) * 8];
        const short8v bh1 = *(const short8v*)&smh[((16 + u)*64 + lane) * 8];
        acc = MFMA32(ah0, bh0, acc);
        acc = MFMA32(ah1, bh1, acc);
        acc = MFMA32(al0, bh0, acc);
        acc = MFMA32(al1, bh1, acc);
        f32x4 r;
        r[0] = ELU(acc[0]); r[1] = ELU(acc[1]); r[2] = ELU(acc[2]); r[3] = ELU(acc[3]);
        ex[u] = r;
    }

    const int scrb = XW_SCR + wave * 4368;
    // ---- dep1: X1[p][i=s][j] = elu(sum_k ex[k]*wd1[s][j][k] + bd1[s][j]) -> scr[p*273+j*17+s]
    #pragma unroll
    for (int j = 0; j < 16; ++j) {
        const float b = sm[XW_BD1 + s*16 + j];
        f32x4 a; a[0] = b; a[1] = b; a[2] = b; a[3] = b;
        #pragma unroll
        for (int kb = 0; kb < 4; ++kb) {
            const float4 w = *(const float4*)&sm[XW_WD1 + s*260 + j*16 + kb*4];
            a += ex[kb*4+0] * w.x; a += ex[kb*4+1] * w.y;
            a += ex[kb*4+2] * w.z; a += ex[kb*4+3] * w.w;
        }
        #pragma unroll
        for (int q = 0; q < 4; ++q)
            sm[scrb + (g*4+q)*273 + j*17 + s] = ELU(a[q]);
    }
    lds_fence();

    // ---- dep2: X2[p][i=s][j] = sum_k X1[p][k][s]*wd2[s][j][k] + bd2[s][j] (no elu)
    f32x4 xr[16];
    #pragma unroll
    for (int k = 0; k < 16; ++k) {
        f32x4 v;
        #pragma unroll
        for (int q = 0; q < 4; ++q)
            v[q] = sm[scrb + (g*4+q)*273 + s*17 + k];
        xr[k] = v;
    }
    f32x4 oj[16];
    #pragma unroll
    for (int j = 0; j < 16; ++j) {
        const float b = sm[XW_BD2 + s*16 + j];
        f32x4 a; a[0] = b; a[1] = b; a[2] = b; a[3] = b;
        #pragma unroll
        for (int kb = 0; kb < 4; ++kb) {
            const float4 w = *(const float4*)&sm[XW_WD2 + s*260 + j*16 + kb*4];
            a += xr[kb*4+0] * w.x; a += xr[kb*4+1] * w.y;
            a += xr[kb*4+2] * w.z; a += xr[kb*4+3] * w.w;
        }
        oj[j] = a;
    }
    #pragma unroll
    for (int q = 0; q < 4; ++q) {
        const int pp = pt0 + g*4 + q;
        #pragma unroll
        for (int jb = 0; jb < 4; ++jb) {
            *(float4*)&x2[pp*256 + s*16 + jb*4] =
                make_float4(oj[jb*4+0][q], oj[jb*4+1][q], oj[jb*4+2][q], oj[jb*4+3][q]);
        }
    }
}

// ---------------- Kernel 2: MFMA features (h1 -> h2 -> cat -> fts_X -> tmp) ----------------
// 8 points/wave, grid 1024 blocks -> 16 waves/CU (VGPR-capped 50% occupancy).
__global__ __launch_bounds__(256, 2) void k_feat(
    const float* __restrict__ rep, const float* __restrict__ pts, const float* __restrict__ fts,
    const float* __restrict__ w1, const float* __restrict__ b1,
    const float* __restrict__ w2, const float* __restrict__ b2,
    const float* __restrict__ wdw, const float* __restrict__ bdw,
    float* __restrict__ xbuf)
{
    __shared__ __align__(16) float swdw[4096];   // [m][c][k^((c&3)<<2)] -> conflict-free b128
    __shared__ float sbdw[256];
    const int tid = threadIdx.x;
    for (int e = tid; e < 4096; e += 256) {
        const int c = e >> 5, m = (e >> 4) & 1, k = e & 15;
        swdw[m*2048 + c*16 + (k ^ ((c & 3) << 2))] = wdw[e];
    }
    sbdw[tid] = bdw[tid & 255];
    __syncthreads();

    const int lane = tid & 63, wave = tid >> 6;
    const int g = lane >> 4, s = lane & 15;

    // ---- one-time per-lane constants ----
    short8v w2f[4][2];
    #pragma unroll
    for (int nt = 0; nt < 4; ++nt)
        #pragma unroll
        for (int h = 0; h < 2; ++h) {
            short8v f;
            #pragma unroll
            for (int e = 0; e < 8; ++e)
                f[e] = f2bf(w2[(h*32 + g*8 + e)*64 + nt*16 + s]);
            w2f[nt][h] = f;
        }
    float w1v[16][3], b1v[16];
    #pragma unroll
    for (int t = 0; t < 2; ++t)
        #pragma unroll
        for (int e = 0; e < 8; ++e) {
            const int j = t*32 + g*8 + e;
            w1v[t*8+e][0] = w1[j]; w1v[t*8+e][1] = w1[64 + j]; w1v[t*8+e][2] = w1[128 + j];
            b1v[t*8+e] = b1[j];
        }
    float b2c[4];
    #pragma unroll
    for (int nt = 0; nt < 4; ++nt) b2c[nt] = b2[nt*16 + s];

    const int gw = blockIdx.x * 4 + wave;   // 0..4095
    const int pt0 = gw * 8;

    // ---- prefetch point pt0 ----
    float pf_f[16]; float4 pf_x; float pf_p0, pf_p1, pf_p2;
    {
        const int pt = pt0;
        #pragma unroll
        for (int ct = 0; ct < 4; ++ct)
            #pragma unroll
            for (int e = 0; e < 4; ++e)
                pf_f[ct*4+e] = fts[pt*1024 + (g*4 + e)*64 + ct*16 + s];
        pf_x = *(const float4*)&xbuf[pt*256 + s*16 + g*4];
        pf_p0 = pts[pt*48 + s*3 + 0] - rep[pt*3 + 0];
        pf_p1 = pts[pt*48 + s*3 + 1] - rep[pt*3 + 1];
        pf_p2 = pts[pt*48 + s*3 + 2] - rep[pt*3 + 2];
    }

    for (int it = 0; it < 8; ++it) {
        const int pt = pt0 + it;
        float cur_f[16];
        #pragma unroll
        for (int i = 0; i < 16; ++i) cur_f[i] = pf_f[i];
        const float4 cur_x = pf_x;
        const float p0 = pf_p0, p1 = pf_p1, p2 = pf_p2;
        if (it < 7) {
            const int np = pt + 1;
            #pragma unroll
            for (int ct = 0; ct < 4; ++ct)
                #pragma unroll
                for (int e = 0; e < 4; ++e)
                    pf_f[ct*4+e] = fts[np*1024 + (g*4 + e)*64 + ct*16 + s];
            pf_x = *(const float4*)&xbuf[np*256 + s*16 + g*4];
            pf_p0 = pts[np*48 + s*3 + 0] - rep[np*3 + 0];
            pf_p1 = pts[np*48 + s*3 + 1] - rep[np*3 + 1];
            pf_p2 = pts[np*48 + s*3 + 2] - rep[np*3 + 2];
        }

        // ---- phase A: h1 in A-frag layout; h2 via 8 MFMA ----
        short8v af0, af1;
        #pragma unroll
        for (int t = 0; t < 2; ++t) {
            short8v f;
            #pragma unroll
            for (int e = 0; e < 8; ++e) {
                float h = b1v[t*8+e] + p0*w1v[t*8+e][0] + p1*w1v[t*8+e][1] + p2*w1v[t*8+e][2];
                h = ELU(h);
                f[e] = f2bf(h);
            }
            if (t == 0) af0 = f; else af1 = f;
        }
        f32x4 hacc[4];
        #pragma unroll
        for (int nt = 0; nt < 4; ++nt) {
            f32x4 a; a[0] = b2c[nt]; a[1] = b2c[nt]; a[2] = b2c[nt]; a[3] = b2c[nt];
            a = MFMA32(af0, w2f[nt][0], a);
            a = MFMA32(af1, w2f[nt][1], a);
            hacc[nt] = a;
        }

        // ---- X2 A-frag (K=16 embedded: slots 0-3) ----
        short8v a2 = (short8v)0;
        a2[0] = f2bf(cur_x.x); a2[1] = f2bf(cur_x.y);
        a2[2] = f2bf(cur_x.z); a2[3] = f2bf(cur_x.w);

        // ---- phase B+C fused per 16-col tile u ----
        #pragma unroll
        for (int u = 0; u < 8; ++u) {
            short8v bfrag = (short8v)0;
            if (u < 4) {
                #pragma unroll
                for (int q = 0; q < 4; ++q) bfrag[q] = f2bf(ELU(hacc[u][q]));
            } else {
                #pragma unroll
                for (int e = 0; e < 4; ++e) bfrag[e] = f2bf(cur_f[(u-4)*4 + e]);
            }
            f32x4 z; z[0] = 0.f; z[1] = 0.f; z[2] = 0.f; z[3] = 0.f;
            const f32x4 fx = MFMA32(a2, bfrag, z);   // fts_X[4g+q][u*16+s]

            const int c = u*16 + s;
            const int ka = c*16 + 4*(g ^ (s & 3));
            const float4 wm0 = *(const float4*)&swdw[ka];
            const float4 wm1 = *(const float4*)&swdw[2048 + ka];
            float q0 = fx[0]*wm0.x + fx[1]*wm0.y + fx[2]*wm0.z + fx[3]*wm0.w;
            float q1 = fx[0]*wm1.x + fx[1]*wm1.y + fx[2]*wm1.z + fx[3]*wm1.w;
            q0 += __shfl_xor(q0, 16); q0 += __shfl_xor(q0, 32);
            q1 += __shfl_xor(q1, 16); q1 += __shfl_xor(q1, 32);
            if (lane < 16) {
                float2 r; r.x = q0 + sbdw[2*c]; r.y = q1 + sbdw[2*c + 1];
                *(float2*)&xbuf[pt*256 + 2*c] = r;
            }
        }
    }
}

// ---------------- Kernel 3: out = elu(tmp(NP,256) @ wpw^T(256,128) + bpw) ----------------
__global__ __launch_bounds__(256) void k_out(
    const float* __restrict__ tmp, const float* __restrict__ wpw,
    const float* __restrict__ bpw, float* __restrict__ out)
{
    __shared__ __align__(16) float At[64*72];   // [k][row], padded stride 72
    __shared__ __align__(16) float Bs[64*128];  // [k][o]
    const int tid = threadIdx.x;
    const int row0 = blockIdx.x * 64;
    const int tr = tid >> 5, tc = tid & 31;
    float acc[8][4];
    #pragma unroll
    for (int i = 0; i < 8; ++i)
        #pragma unroll
        for (int j = 0; j < 4; ++j) acc[i][j] = 0.f;

    for (int kb = 0; kb < 4; ++kb) {
        #pragma unroll
        for (int i = 0; i < 16; ++i) {
            const int e = tid + i*256;
            const int r = e >> 6, k = e & 63;
            At[k*72 + r] = tmp[(row0 + r)*256 + kb*64 + k];
        }
        #pragma unroll
        for (int i = 0; i < 32; ++i) {
            const int e = tid + i*256;
            const int o = e >> 6, k = e & 63;
            Bs[k*128 + o] = wpw[o*256 + kb*64 + k];
        }
        __syncthreads();
        #pragma unroll 4
        for (int k = 0; k < 64; ++k) {
            const float4 aa = *(const float4*)&At[k*72 + 8*tr];
            const float4 ab = *(const float4*)&At[k*72 + 8*tr + 4];
            const float4 bv = *(const float4*)&Bs[k*128 + 4*tc];
            const float av[8] = {aa.x, aa.y, aa.z, aa.w, ab.x, ab.y, ab.z, ab.w};
            #pragma unroll
            for (int ri = 0; ri < 8; ++ri) {
                acc[ri][0] += av[ri]*bv.x; acc[ri][1] += av[ri]*bv.y;
                acc[ri][2] += av[ri]*bv.z; acc[ri][3] += av[ri]*bv.w;
            }
        }
        __syncthreads();
    }
    const float4 bb = *(const float4*)&bpw[4*tc];
    #pragma unroll
    for (int ri = 0; ri < 8; ++ri) {
        float4 r;
        r.x = ELU(acc[ri][0] + bb.x);
        r.y = ELU(acc[ri][1] + bb.y);
        r.z = ELU(acc[ri][2] + bb.z);
        r.w = ELU(acc[ri][3] + bb.w);
        *(float4*)&out[(row0 + 8*tr + ri)*128 + 4*tc] = r;
    }
}

extern "C" void kernel_launch(void* const* d_in, const int* in_sizes, int n_in,
                              void* d_out, int out_size, void* d_ws, size_t ws_size,
                              hipStream_t stream)
{
    (void)in_sizes; (void)n_in; (void)out_size; (void)ws_size;
    const float* rep   = (const float*)d_in[0];
    const float* pts   = (const float*)d_in[1];
    const float* fts   = (const float*)d_in[2];
    const float* w1    = (const float*)d_in[3];
    const float* b1    = (const float*)d_in[4];
    const float* w2    = (const float*)d_in[5];
    const float* b2    = (const float*)d_in[6];
    const float* wconv = (const float*)d_in[7];
    const float* bconv = (const float*)d_in[8];
    const float* wdep1 = (const float*)d_in[9];
    const float* bdep1 = (const float*)d_in[10];
    const float* wdep2 = (const float*)d_in[11];
    const float* bdep2 = (const float*)d_in[12];
    const float* wdw   = (const float*)d_in[13];
    const float* bdw   = (const float*)d_in[14];
    const float* wpw   = (const float*)d_in[15];
    const float* bpw   = (const float*)d_in[16];
    float* out  = (float*)d_out;
    float* xbuf = (float*)d_ws;   // 32768*256 floats = 33.5 MB

    hipFuncSetAttribute((const void*)k_xform, hipFuncAttributeMaxDynamicSharedMemorySize, XW_TOTAL*4);

    k_xform<<<dim3(512),  dim3(256), XW_TOTAL*4, stream>>>(rep, pts, wconv, bconv, wdep1, bdep1, wdep2, bdep2, xbuf);
    k_feat <<<dim3(1024), dim3(256), 0, stream>>>(rep, pts, fts, w1, b1, w2, b2, wdw, bdw, xbuf);
    k_out  <<<dim3(512),  dim3(256), 0, stream>>>(xbuf, wpw, bpw, out);
}